// Round 1
// baseline (853.340 us; speedup 1.0000x reference)
//
#include <hip/hip_runtime.h>

#define Bb 64
#define Ss 1000
#define Kk 12
#define Nn 80

// 0.5 * N * log(2*pi) for N=80
#define CTERM 73.51508265637381f

__global__ __launch_bounds__(256) void mvn_ll_kernel(
    const float* __restrict__ x,      // (B,S,N)
    const float* __restrict__ mu,     // (B,K,N)
    const float* __restrict__ sigma,  // (B,K,N,N)
    float* __restrict__ out)          // (B,S,K)
{
    __shared__ float Ls[Nn * Nn];
    __shared__ float invd[Nn];
    __shared__ float mus[Nn];
    __shared__ float logdet_s;

    const int bk  = blockIdx.x;        // b*K + k
    const int b   = bk / Kk;
    const int k   = bk - b * Kk;
    const int tid = threadIdx.x;
    const int nt  = blockDim.x;

    // ---- Phase 0: stage sigma + mu into LDS ----
    const float* sp = sigma + (size_t)bk * Nn * Nn;
    for (int t = tid; t < Nn * Nn; t += nt) Ls[t] = sp[t];
    if (tid < Nn) mus[tid] = mu[(size_t)bk * Nn + tid];
    __syncthreads();
    if (tid < Nn) Ls[tid * Nn + tid] += 1e-5f;   // add_epsilon (diag)
    __syncthreads();

    // ---- Phase 1: in-place Cholesky (lower), right-looking ----
    for (int j = 0; j < Nn; ++j) {
        if (tid == 0) {
            float d = sqrtf(Ls[j * Nn + j]);
            Ls[j * Nn + j] = d;
            invd[j] = 1.0f / d;
        }
        __syncthreads();
        const float inv = invd[j];
        for (int i = j + 1 + tid; i < Nn; i += nt) Ls[i * Nn + j] *= inv;
        __syncthreads();
        const int m = Nn - 1 - j;  // trailing block size
        for (int idx = tid; idx < m * m; idx += nt) {
            const int r = idx / m;
            const int c = idx - r * m;
            if (c <= r) {
                const int i = j + 1 + r;
                const int l = j + 1 + c;
                Ls[i * Nn + l] -= Ls[i * Nn + j] * Ls[l * Nn + j];
            }
        }
        __syncthreads();
    }
    if (tid == 0) {
        float acc = 0.0f;
        for (int j = 0; j < Nn; ++j) acc += logf(Ls[j * Nn + j]);
        logdet_s = acc;
    }
    __syncthreads();

    const float ld = logdet_s;

    // ---- Phase 2: per-thread forward substitution over sequence positions ----
    for (int s = tid; s < Ss; s += nt) {
        const float4* xp = (const float4*)(x + ((size_t)b * Ss + s) * Nn);
        float a[Nn];
        #pragma unroll
        for (int q = 0; q < Nn / 4; ++q) {
            const float4 v = xp[q];
            a[4 * q + 0] = v.x - mus[4 * q + 0];
            a[4 * q + 1] = v.y - mus[4 * q + 1];
            a[4 * q + 2] = v.z - mus[4 * q + 2];
            a[4 * q + 3] = v.w - mus[4 * q + 3];
        }
        // solve L z = a in place (z overwrites a)
        #pragma unroll
        for (int i = 0; i < Nn; ++i) {
            float t = a[i];
            #pragma unroll
            for (int j = 0; j < i; ++j) {
                t = fmaf(-Ls[i * Nn + j], a[j], t);
            }
            a[i] = t * invd[i];
        }
        float quad = 0.0f;
        #pragma unroll
        for (int i = 0; i < Nn; ++i) quad = fmaf(a[i], a[i], quad);

        out[((size_t)b * Ss + s) * Kk + k] = -0.5f * quad - ld - CTERM;
    }
}

extern "C" void kernel_launch(void* const* d_in, const int* in_sizes, int n_in,
                              void* d_out, int out_size, void* d_ws, size_t ws_size,
                              hipStream_t stream) {
    const float* x     = (const float*)d_in[0];
    const float* mu    = (const float*)d_in[1];
    const float* sigma = (const float*)d_in[2];
    float* out = (float*)d_out;

    dim3 grid(Bb * Kk);
    dim3 block(256);
    mvn_ll_kernel<<<grid, block, 0, stream>>>(x, mu, sigma, out);
}

// Round 2
// 651.088 us; speedup vs baseline: 1.3106x; 1.3106x over previous
//
#include <hip/hip_runtime.h>

#define Bb 64
#define Ss 1000
#define Kk 12
#define Nn 80
#define CTERM 73.51508265637381f   // 0.5 * 80 * log(2*pi)

// ---------------- Kernel 1: per (b,k) Cholesky -> W = L^{-1}, u = W*mu, logdet ----
#define ST1 81   // padded LDS stride (odd -> conflict-free for stride-ST1 column walks)

__global__ __launch_bounds__(128) void prep_kernel(
    const float* __restrict__ mu,
    const float* __restrict__ sigma,
    float* __restrict__ wsW,   // [768][80*80] col-major: wsW[bk][k*80+m] = W[m][k]
    float* __restrict__ wsU,   // [768][80]    u = W*mu
    float* __restrict__ wsL)   // [768]        logdet_half
{
    __shared__ float Ls[Nn * ST1];
    __shared__ float Wm[Nn * ST1];   // row-major W (row m contiguous), zero-init
    __shared__ float mus[Nn];
    __shared__ float invd[Nn];

    const int bk  = blockIdx.x;
    const int tid = threadIdx.x;

    const float* sp = sigma + (size_t)bk * Nn * Nn;
    for (int t = tid; t < Nn * Nn; t += 128) {
        int r = t / Nn, c = t % Nn;
        Ls[r * ST1 + c] = sp[t];
    }
    for (int t = tid; t < Nn * ST1; t += 128) Wm[t] = 0.0f;
    if (tid < Nn) mus[tid] = mu[(size_t)bk * Nn + tid];
    __syncthreads();
    if (tid < Nn) Ls[tid * ST1 + tid] += 1e-5f;
    __syncthreads();

    // ---- Cholesky (right-looking), padded stride kills bank conflicts ----
    for (int j = 0; j < Nn; ++j) {
        if (tid == 0) {
            float d = sqrtf(Ls[j * ST1 + j]);
            Ls[j * ST1 + j] = d;
            invd[j] = 1.0f / d;
        }
        __syncthreads();
        const float inv = invd[j];
        for (int i = j + 1 + tid; i < Nn; i += 128) Ls[i * ST1 + j] *= inv;
        __syncthreads();
        for (int t = tid; t < Nn * Nn; t += 128) {
            int r = t / Nn, c = t % Nn;
            if (r > j && c > j && c <= r) {
                Ls[r * ST1 + c] -= Ls[r * ST1 + j] * Ls[c * ST1 + j];
            }
        }
        __syncthreads();
    }

    if (tid == 0) {
        float a = 0.0f;
        for (int j = 0; j < Nn; ++j) a += logf(Ls[j * ST1 + j]);
        wsL[bk] = a;
    }

    // ---- Triangular inversion: thread j owns column j of W (no barriers needed:
    //      each column only reads its own prior writes; Ls/invd are final).
    //      Uniform loops (m from 0, zeros in Wm make it exact): broadcast + contiguous reads.
    const int j = tid;
    if (j < Nn) {
        for (int i = 0; i < Nn; ++i) {
            float s = 0.0f;
            for (int m = 0; m < i; ++m)
                s = fmaf(Ls[i * ST1 + m], Wm[m * ST1 + j], s);
            float del = (i == j) ? 1.0f : 0.0f;
            Wm[i * ST1 + j] = (del - s) * invd[i];
        }
    }
    __syncthreads();

    // u = W * mu  (thread m does a length-(m+1) dot)
    if (tid < Nn) {
        float a = 0.0f;
        for (int k = 0; k <= tid; ++k) a = fmaf(Wm[tid * ST1 + k], mus[k], a);
        wsU[bk * Nn + tid] = a;
    }

    // store W col-major, coalesced
    for (int t = tid; t < Nn * Nn; t += 128) {
        int k = t / Nn, m = t % Nn;
        wsW[(size_t)bk * Nn * Nn + t] = Wm[m * ST1 + k];
    }
}

// ---------------- Kernel 2: GEMM  Z = W * X^T - u,  quad = colnorm^2 ----------------
#define TS  128    // s-tile
#define STX 132    // XT stride (mod 32 == 4, 16B-aligned rows)

__global__ __launch_bounds__(320) void ll_kernel(
    const float* __restrict__ x,
    const float* __restrict__ wsW,
    const float* __restrict__ wsU,
    const float* __restrict__ wsL,
    float* __restrict__ out)
{
    __shared__ float WC[Nn * Nn];    // col-major W: WC[k*80+m]  (25.6 KB)
    __shared__ float XT[Nn * STX];   // XT[k*STX+s]              (42.2 KB)
    __shared__ float uS[Nn];

    const int bk  = blockIdx.x;          // b*K+k
    const int st  = blockIdx.y;          // s-tile
    const int b   = bk / Kk;
    const int k   = bk - b * Kk;
    const int s0  = st * TS;
    const int tid = threadIdx.x;
    const int rg  = tid >> 5;            // 0..9  -> rows rg*8..rg*8+7
    const int cg  = tid & 31;            // 0..31 -> cols cg*4..cg*4+3

    // load W (coalesced float4, same layout)
    {
        const float4* wp = (const float4*)(wsW + (size_t)bk * Nn * Nn);
        float4* wl = (float4*)WC;
        #pragma unroll
        for (int t = 0; t < 5; ++t) wl[tid + 320 * t] = wp[tid + 320 * t];
    }
    if (tid < Nn) uS[tid] = wsU[bk * Nn + tid];

    // load + transpose x tile: XT[k][s]
    #pragma unroll
    for (int i = 0; i < 8; ++i) {
        int cI = tid + 320 * i;          // 0..2559
        int sr = cI / 20, q = cI % 20;   // row in tile, float4 index in row
        int s  = s0 + sr;
        float4 v = make_float4(0.f, 0.f, 0.f, 0.f);
        if (s < Ss) v = *(const float4*)(x + ((size_t)b * Ss + s) * Nn + 4 * q);
        XT[(4 * q + 0) * STX + sr] = v.x;
        XT[(4 * q + 1) * STX + sr] = v.y;
        XT[(4 * q + 2) * STX + sr] = v.z;
        XT[(4 * q + 3) * STX + sr] = v.w;
    }
    __syncthreads();

    const int r0 = rg * 8;
    float acc[8][4];
    #pragma unroll
    for (int r = 0; r < 8; ++r) {
        float nu = -uS[r0 + r];
        #pragma unroll
        for (int j = 0; j < 4; ++j) acc[r][j] = nu;
    }

    // triangular k-loop: rows r0..r0+7 only need k <= r0+7 (W upper part is 0)
    const int kmax = r0 + 8;
    for (int kk = 0; kk < kmax; ++kk) {
        float4 w0 = *(const float4*)&WC[kk * Nn + r0];
        float4 w1 = *(const float4*)&WC[kk * Nn + r0 + 4];
        float4 xf = *(const float4*)&XT[kk * STX + 4 * cg];
        float wv[8] = {w0.x, w0.y, w0.z, w0.w, w1.x, w1.y, w1.z, w1.w};
        float xv[4] = {xf.x, xf.y, xf.z, xf.w};
        #pragma unroll
        for (int r = 0; r < 8; ++r)
            #pragma unroll
            for (int j = 0; j < 4; ++j)
                acc[r][j] = fmaf(wv[r], xv[j], acc[r][j]);
    }
    __syncthreads();

    // partial quad per (thread, col) -> reduce over 10 row-groups (reuse XT)
    float* red = XT;
    #pragma unroll
    for (int j = 0; j < 4; ++j) {
        float p = 0.0f;
        #pragma unroll
        for (int r = 0; r < 8; ++r) p = fmaf(acc[r][j], acc[r][j], p);
        red[rg * TS + 4 * cg + j] = p;
    }
    __syncthreads();

    if (tid < TS) {
        float q = 0.0f;
        #pragma unroll
        for (int g = 0; g < 10; ++g) q += red[g * TS + tid];
        int s = s0 + tid;
        if (s < Ss) {
            float ld = wsL[bk];
            out[((size_t)b * Ss + s) * Kk + k] = -0.5f * q - ld - CTERM;
        }
    }
}

// ---------------- Fallback (round-1 kernel) if workspace is too small ----------------
__global__ __launch_bounds__(256) void mvn_ll_fallback(
    const float* __restrict__ x, const float* __restrict__ mu,
    const float* __restrict__ sigma, float* __restrict__ out)
{
    __shared__ float Ls[Nn * ST1];
    __shared__ float invd[Nn];
    __shared__ float mus[Nn];
    __shared__ float logdet_s;

    const int bk = blockIdx.x, b = bk / Kk, k = bk - b * Kk;
    const int tid = threadIdx.x, nt = blockDim.x;

    const float* sp = sigma + (size_t)bk * Nn * Nn;
    for (int t = tid; t < Nn * Nn; t += nt) Ls[(t / Nn) * ST1 + (t % Nn)] = sp[t];
    if (tid < Nn) mus[tid] = mu[(size_t)bk * Nn + tid];
    __syncthreads();
    if (tid < Nn) Ls[tid * ST1 + tid] += 1e-5f;
    __syncthreads();
    for (int j = 0; j < Nn; ++j) {
        if (tid == 0) {
            float d = sqrtf(Ls[j * ST1 + j]);
            Ls[j * ST1 + j] = d; invd[j] = 1.0f / d;
        }
        __syncthreads();
        const float inv = invd[j];
        for (int i = j + 1 + tid; i < Nn; i += nt) Ls[i * ST1 + j] *= inv;
        __syncthreads();
        for (int t = tid; t < Nn * Nn; t += nt) {
            int r = t / Nn, c = t % Nn;
            if (r > j && c > j && c <= r)
                Ls[r * ST1 + c] -= Ls[r * ST1 + j] * Ls[c * ST1 + j];
        }
        __syncthreads();
    }
    if (tid == 0) {
        float a = 0.f; for (int j = 0; j < Nn; ++j) a += logf(Ls[j * ST1 + j]);
        logdet_s = a;
    }
    __syncthreads();
    const float ld = logdet_s;
    for (int s = tid; s < Ss; s += nt) {
        const float4* xp = (const float4*)(x + ((size_t)b * Ss + s) * Nn);
        float a[Nn];
        #pragma unroll
        for (int q = 0; q < Nn / 4; ++q) {
            float4 v = xp[q];
            a[4*q+0] = v.x - mus[4*q+0]; a[4*q+1] = v.y - mus[4*q+1];
            a[4*q+2] = v.z - mus[4*q+2]; a[4*q+3] = v.w - mus[4*q+3];
        }
        #pragma unroll
        for (int i = 0; i < Nn; ++i) {
            float t = a[i];
            #pragma unroll
            for (int j = 0; j < i; ++j) t = fmaf(-Ls[i * ST1 + j], a[j], t);
            a[i] = t * invd[i];
        }
        float quad = 0.f;
        #pragma unroll
        for (int i = 0; i < Nn; ++i) quad = fmaf(a[i], a[i], quad);
        out[((size_t)b * Ss + s) * Kk + k] = -0.5f * quad - ld - CTERM;
    }
}

extern "C" void kernel_launch(void* const* d_in, const int* in_sizes, int n_in,
                              void* d_out, int out_size, void* d_ws, size_t ws_size,
                              hipStream_t stream) {
    const float* x     = (const float*)d_in[0];
    const float* mu    = (const float*)d_in[1];
    const float* sigma = (const float*)d_in[2];
    float* out = (float*)d_out;

    const size_t nBK = (size_t)Bb * Kk;                      // 768
    const size_t need = nBK * Nn * Nn * 4 + nBK * Nn * 4 + nBK * 4;

    if (ws_size >= need) {
        float* wsW = (float*)d_ws;
        float* wsU = wsW + nBK * Nn * Nn;
        float* wsL = wsU + nBK * Nn;
        prep_kernel<<<dim3(Bb * Kk), dim3(128), 0, stream>>>(mu, sigma, wsW, wsU, wsL);
        ll_kernel<<<dim3(Bb * Kk, (Ss + TS - 1) / TS), dim3(320), 0, stream>>>(x, wsW, wsU, wsL, out);
    } else {
        mvn_ll_fallback<<<dim3(Bb * Kk), dim3(256), 0, stream>>>(x, mu, sigma, out);
    }
}

// Round 3
// 590.639 us; speedup vs baseline: 1.4448x; 1.1023x over previous
//
#include <hip/hip_runtime.h>

#define Bb 64
#define Ss 1000
#define Kk 12
#define Nn 80
#define CTERM 73.51508265637381f   // 0.5 * 80 * log(2*pi)
#define ST1 81                     // padded LDS stride (odd -> conflict-free column walks)

// ---------------- Kernel 1: per (b,k) Cholesky -> W = L^{-1}, logdet ----------------
__global__ __launch_bounds__(128) void prep_kernel(
    const float* __restrict__ sigma,
    float* __restrict__ wsW,   // [768][80*80] col-major: wsW[bk][k*80+m] = W[m][k]
    float* __restrict__ wsL)   // [768] logdet_half
{
    __shared__ float Ls[Nn * ST1];
    __shared__ float Wm[Nn * ST1];   // row-major W (zero-init; strictly-upper stays 0)
    __shared__ float invd[Nn];

    const int bk  = blockIdx.x;
    const int tid = threadIdx.x;

    // stage sigma via b128 global reads
    const float4* sp4 = (const float4*)(sigma + (size_t)bk * Nn * Nn);
    #pragma unroll
    for (int it = 0; it < 13; ++it) {
        int ci = tid + 128 * it;        // float4 index, 0..1599
        if (ci < 1600) {
            float4 v = sp4[ci];
            int r = ci / 20, c4 = 4 * (ci - 20 * (ci / 20));
            float* dst = &Ls[r * ST1 + c4];
            dst[0] = v.x; dst[1] = v.y; dst[2] = v.z; dst[3] = v.w;
        }
    }
    for (int t = tid; t < Nn * ST1; t += 128) Wm[t] = 0.0f;
    __syncthreads();
    if (tid < Nn) Ls[tid * ST1 + tid] += 1e-5f;
    __syncthreads();

    // ---- Cholesky: 2 barriers/j, uniform column loop, no integer div ----
    float ldacc = 0.0f;
    for (int j = 0; j < Nn; ++j) {
        float piv = Ls[j * ST1 + j];          // broadcast read (final after prev barrier)
        float inv = rsqrtf(piv);
        if (tid == 0) { invd[j] = inv; ldacc += logf(inv); }
        int i = j + 1 + tid;
        if (i < Nn) Ls[i * ST1 + j] *= inv;   // single shot: <=79 rows, 128 threads
        __syncthreads();
        for (int c = j + 1; c < Nn; ++c) {    // uniform bound; lanes = rows c..79
            int r = c + tid;
            if (r < Nn)
                Ls[r * ST1 + c] = fmaf(-Ls[r * ST1 + j], Ls[c * ST1 + j], Ls[r * ST1 + c]);
        }
        __syncthreads();
    }
    if (tid == 0) wsL[bk] = -ldacc;           // logdet_half = -sum log(invd)

    // ---- Triangular inversion: thread=column, wave-uniform lower bounds ----
    const int col = tid;
    const int i0  = (tid >= 64) ? 64 : 0;     // wave 1's columns are all >= 64
    if (col < Nn) {
        for (int i = i0; i < Nn; ++i) {
            float s0 = 0.0f, s1 = 0.0f;
            int m = i0;
            for (; m + 1 < i; m += 2) {
                s0 = fmaf(Ls[i * ST1 + m],       Wm[m * ST1 + col],       s0);
                s1 = fmaf(Ls[i * ST1 + m + 1],   Wm[(m + 1) * ST1 + col], s1);
            }
            if (m < i) s0 = fmaf(Ls[i * ST1 + m], Wm[m * ST1 + col], s0);
            float del = (i == col) ? 1.0f : 0.0f;
            Wm[i * ST1 + col] = (del - (s0 + s1)) * invd[i];
        }
    }
    __syncthreads();

    // store W col-major, coalesced
    for (int t = tid; t < Nn * Nn; t += 128) {
        int k = t / Nn, m2 = t - k * Nn;
        wsW[(size_t)bk * Nn * Nn + t] = Wm[m2 * ST1 + k];
    }
}

// ---------------- Kernel 2: balanced triangular GEMM  Z = W*(X - mu), quad ----------
#define TS  128
#define STX 132

__global__ __launch_bounds__(320) void ll_kernel(
    const float* __restrict__ x,
    const float* __restrict__ mu,
    const float* __restrict__ wsW,
    const float* __restrict__ wsL,
    float* __restrict__ out)
{
    __shared__ float WC[Nn * Nn];    // col-major W
    __shared__ float XT[Nn * STX];   // XT[n][s] = x[s][n] - mu[n]; reused as reduce buf
    __shared__ float mus[Nn];

    const int bk  = blockIdx.x;
    const int st  = blockIdx.y;
    const int b   = bk / Kk;
    const int k   = bk - b * Kk;
    const int s0  = st * TS;
    const int tid = threadIdx.x;
    const int rg  = tid >> 5;        // 0..9
    const int cg  = tid & 31;        // 0..31

    if (tid < Nn) mus[tid] = mu[(size_t)bk * Nn + tid];
    {
        const float4* wp = (const float4*)(wsW + (size_t)bk * Nn * Nn);
        float4* wl = (float4*)WC;
        #pragma unroll
        for (int t = 0; t < 5; ++t) wl[tid + 320 * t] = wp[tid + 320 * t];
    }
    __syncthreads();

    // stage + transpose (x - mu); rotated component order cuts write conflicts
    #pragma unroll
    for (int it = 0; it < 8; ++it) {
        int cI = tid + 320 * it;                 // 0..2559
        int sr = cI / 20, q = cI - 20 * sr;
        int s  = s0 + sr;
        float4 v = make_float4(0.f, 0.f, 0.f, 0.f);
        if (s < Ss) v = *(const float4*)(x + ((size_t)b * Ss + s) * Nn + 4 * q);
        float v0 = v.x - mus[4 * q + 0];
        float v1 = v.y - mus[4 * q + 1];
        float v2 = v.z - mus[4 * q + 2];
        float v3 = v.w - mus[4 * q + 3];
        #pragma unroll
        for (int n = 0; n < 4; ++n) {
            int i = (n + q) & 3;
            float val = (i == 0) ? v0 : (i == 1) ? v1 : (i == 2) ? v2 : v3;
            XT[(4 * q + i) * STX + sr] = val;
        }
    }
    __syncthreads();

    // balanced split tile: rows [4rg,4rg+4) + [76-4rg,80-4rg); uniform 1344 FMA/thread
    const int a0 = 4 * rg;
    const int b0 = 76 - 4 * rg;
    float aA[4][4], aB[4][4];
    #pragma unroll
    for (int r = 0; r < 4; ++r)
        #pragma unroll
        for (int j = 0; j < 4; ++j) { aA[r][j] = 0.f; aB[r][j] = 0.f; }

    const int e1 = a0 + 4;
    const int e2 = b0 + 4;
    int kk = 0;
    #pragma unroll 4
    for (; kk < e1; ++kk) {
        float4 xf = *(const float4*)&XT[kk * STX + 4 * cg];
        float4 wa = *(const float4*)&WC[kk * Nn + a0];
        float4 wb = *(const float4*)&WC[kk * Nn + b0];
        float xv[4]  = {xf.x, xf.y, xf.z, xf.w};
        float wav[4] = {wa.x, wa.y, wa.z, wa.w};
        float wbv[4] = {wb.x, wb.y, wb.z, wb.w};
        #pragma unroll
        for (int r = 0; r < 4; ++r)
            #pragma unroll
            for (int j = 0; j < 4; ++j) {
                aA[r][j] = fmaf(wav[r], xv[j], aA[r][j]);
                aB[r][j] = fmaf(wbv[r], xv[j], aB[r][j]);
            }
    }
    #pragma unroll 4
    for (; kk < e2; ++kk) {
        float4 xf = *(const float4*)&XT[kk * STX + 4 * cg];
        float4 wb = *(const float4*)&WC[kk * Nn + b0];
        float xv[4]  = {xf.x, xf.y, xf.z, xf.w};
        float wbv[4] = {wb.x, wb.y, wb.z, wb.w};
        #pragma unroll
        for (int r = 0; r < 4; ++r)
            #pragma unroll
            for (int j = 0; j < 4; ++j)
                aB[r][j] = fmaf(wbv[r], xv[j], aB[r][j]);
    }
    __syncthreads();

    // per-(thread,col) partial quad -> b128 write -> reduce 10 row-groups
    float pj[4];
    #pragma unroll
    for (int j = 0; j < 4; ++j) {
        float t = 0.f;
        #pragma unroll
        for (int r = 0; r < 4; ++r) {
            t = fmaf(aA[r][j], aA[r][j], t);
            t = fmaf(aB[r][j], aB[r][j], t);
        }
        pj[j] = t;
    }
    *(float4*)&XT[rg * TS + 4 * cg] = make_float4(pj[0], pj[1], pj[2], pj[3]);
    __syncthreads();

    if (tid < TS) {
        float q2 = 0.f;
        #pragma unroll
        for (int g = 0; g < 10; ++g) q2 += XT[g * TS + tid];
        int s = s0 + tid;
        if (s < Ss)
            out[((size_t)b * Ss + s) * Kk + k] = -0.5f * q2 - wsL[bk] - CTERM;
    }
}

// ---------------- Fallback if workspace too small ----------------
__global__ __launch_bounds__(256) void mvn_ll_fallback(
    const float* __restrict__ x, const float* __restrict__ mu,
    const float* __restrict__ sigma, float* __restrict__ out)
{
    __shared__ float Ls[Nn * ST1];
    __shared__ float invd[Nn];
    __shared__ float mus[Nn];
    __shared__ float logdet_s;

    const int bk = blockIdx.x, b = bk / Kk, k = bk - b * Kk;
    const int tid = threadIdx.x, nt = blockDim.x;

    const float* sp = sigma + (size_t)bk * Nn * Nn;
    for (int t = tid; t < Nn * Nn; t += nt) Ls[(t / Nn) * ST1 + (t % Nn)] = sp[t];
    if (tid < Nn) mus[tid] = mu[(size_t)bk * Nn + tid];
    __syncthreads();
    if (tid < Nn) Ls[tid * ST1 + tid] += 1e-5f;
    __syncthreads();
    for (int j = 0; j < Nn; ++j) {
        if (tid == 0) {
            float d = sqrtf(Ls[j * ST1 + j]);
            Ls[j * ST1 + j] = d; invd[j] = 1.0f / d;
        }
        __syncthreads();
        const float inv = invd[j];
        for (int i = j + 1 + tid; i < Nn; i += nt) Ls[i * ST1 + j] *= inv;
        __syncthreads();
        for (int t = tid; t < Nn * Nn; t += nt) {
            int r = t / Nn, c = t % Nn;
            if (r > j && c > j && c <= r)
                Ls[r * ST1 + c] -= Ls[r * ST1 + j] * Ls[c * ST1 + j];
        }
        __syncthreads();
    }
    if (tid == 0) {
        float a = 0.f; for (int j = 0; j < Nn; ++j) a += logf(Ls[j * ST1 + j]);
        logdet_s = a;
    }
    __syncthreads();
    const float ld = logdet_s;
    for (int s = tid; s < Ss; s += nt) {
        const float4* xp = (const float4*)(x + ((size_t)b * Ss + s) * Nn);
        float a[Nn];
        #pragma unroll
        for (int q = 0; q < Nn / 4; ++q) {
            float4 v = xp[q];
            a[4*q+0] = v.x - mus[4*q+0]; a[4*q+1] = v.y - mus[4*q+1];
            a[4*q+2] = v.z - mus[4*q+2]; a[4*q+3] = v.w - mus[4*q+3];
        }
        #pragma unroll
        for (int i = 0; i < Nn; ++i) {
            float t = a[i];
            #pragma unroll
            for (int j = 0; j < i; ++j) t = fmaf(-Ls[i * ST1 + j], a[j], t);
            a[i] = t * invd[i];
        }
        float quad = 0.f;
        #pragma unroll
        for (int i = 0; i < Nn; ++i) quad = fmaf(a[i], a[i], quad);
        out[((size_t)b * Ss + s) * Kk + k] = -0.5f * quad - ld - CTERM;
    }
}

extern "C" void kernel_launch(void* const* d_in, const int* in_sizes, int n_in,
                              void* d_out, int out_size, void* d_ws, size_t ws_size,
                              hipStream_t stream) {
    const float* x     = (const float*)d_in[0];
    const float* mu    = (const float*)d_in[1];
    const float* sigma = (const float*)d_in[2];
    float* out = (float*)d_out;

    const size_t nBK  = (size_t)Bb * Kk;                    // 768
    const size_t need = nBK * Nn * Nn * 4 + nBK * 4;

    if (ws_size >= need) {
        float* wsW = (float*)d_ws;
        float* wsL = wsW + nBK * Nn * Nn;
        prep_kernel<<<dim3(Bb * Kk), dim3(128), 0, stream>>>(sigma, wsW, wsL);
        ll_kernel<<<dim3(Bb * Kk, (Ss + TS - 1) / TS), dim3(320), 0, stream>>>(x, mu, wsW, wsL, out);
    } else {
        mvn_ll_fallback<<<dim3(Bb * Kk), dim3(256), 0, stream>>>(x, mu, sigma, out);
    }
}

// Round 4
// 492.112 us; speedup vs baseline: 1.7340x; 1.2002x over previous
//
#include <hip/hip_runtime.h>

#define Bb 64
#define Ss 1000
#define Kk 12
#define Nn 80
#define CTERM 73.51508265637381f   // 0.5 * 80 * log(2*pi)
#define ST1 81                     // padded LDS stride (odd -> conflict-free column walks)

// ---------------- Kernel 1: per (b,k) Cholesky -> W = L^{-1} (packed in-place), logdet ----
// Ls strictly-lower + scratch diag: L.  Upper incl diag (Ls[col*ST1+i], i>=col): W[i][col].
__global__ __launch_bounds__(256) void prep_kernel(
    const float* __restrict__ sigma,
    float* __restrict__ wsW,   // [768][80*80]: wsW[bk][k*80+m] = W[m][k] (zeros above diag)
    float* __restrict__ wsL)   // [768] logdet_half
{
    __shared__ float Ls[Nn * ST1];   // 25.9 KB
    __shared__ float invd[Nn];

    const int bk  = blockIdx.x;
    const int tid = threadIdx.x;

    // stage sigma (row-major, stride-81)
    const float4* sp4 = (const float4*)(sigma + (size_t)bk * Nn * Nn);
    #pragma unroll
    for (int it = 0; it < 7; ++it) {
        int ci = tid + 256 * it;          // float4 index 0..1599
        if (ci < 1600) {
            float4 v = sp4[ci];
            int r = ci / 20, c4 = 4 * (ci - 20 * (ci / 20));
            float* dst = &Ls[r * ST1 + c4];
            dst[0] = v.x; dst[1] = v.y; dst[2] = v.z; dst[3] = v.w;
        }
    }
    __syncthreads();
    if (tid < Nn) Ls[tid * ST1 + tid] += 1e-5f;
    __syncthreads();

    // ---- Cholesky, right-looking; trailing update = 4-col rectangle x 2 groups ----
    float ldacc = 0.0f;
    const int rr  = tid & 127;            // row lane
    const int cg2 = tid >> 7;             // column group 0/1
    for (int j = 0; j < Nn; ++j) {
        float piv = Ls[j * ST1 + j];
        float inv = rsqrtf(piv);
        if (tid == 0) { invd[j] = inv; ldacc += logf(inv); }
        int i = j + 1 + tid;
        if (i < Nn) Ls[i * ST1 + j] *= inv;
        __syncthreads();

        const int r = j + 1 + rr;
        if (r < Nn) {
            const float lr = Ls[r * ST1 + j];
            float* row = &Ls[r * ST1];
            for (int c0 = j + 1 + 4 * cg2; c0 < Nn; c0 += 8) {
                int c1 = c0 + 1, c2 = c0 + 2, c3 = c0 + 3;
                int c1c = (c1 < Nn) ? c1 : Nn - 1;
                int c2c = (c2 < Nn) ? c2 : Nn - 1;
                int c3c = (c3 < Nn) ? c3 : Nn - 1;
                float p0 = Ls[c0  * ST1 + j];
                float p1 = Ls[c1c * ST1 + j];
                float p2 = Ls[c2c * ST1 + j];
                float p3 = Ls[c3c * ST1 + j];
                row[c0] = fmaf(-lr, p0, row[c0]);            // rectangle: upper garbage OK
                if (c1 < Nn) row[c1] = fmaf(-lr, p1, row[c1]);
                if (c2 < Nn) row[c2] = fmaf(-lr, p2, row[c2]);
                if (c3 < Nn) row[c3] = fmaf(-lr, p3, row[c3]);
            }
        }
        __syncthreads();
    }
    if (tid == 0) wsL[bk] = -ldacc;

    // ---- Triangular inversion into the upper triangle: W[i][col] -> Ls[col*ST1+i] ----
    // Lane = column. Rows of Ls are lane-private (row col written only by lane col);
    // broadcast reads touch only strictly-lower L. No barriers needed.
    const int col = tid;
    if (col < Nn) {
        const int i0 = (tid >= 64) ? 64 : 0;   // wave-uniform start
        for (int i = i0; i < Nn; ++i) {
            float s0 = 0.f, s1 = 0.f, s2 = 0.f, s3 = 0.f;
            int m = i0;
            for (; m + 3 < i; m += 4) {
                float l0 = Ls[i * ST1 + m];
                float l1 = Ls[i * ST1 + m + 1];
                float l2 = Ls[i * ST1 + m + 2];
                float l3 = Ls[i * ST1 + m + 3];
                float w0 = Ls[col * ST1 + m];
                float w1 = Ls[col * ST1 + m + 1];
                float w2 = Ls[col * ST1 + m + 2];
                float w3 = Ls[col * ST1 + m + 3];
                w0 = (m     >= col) ? w0 : 0.f;
                w1 = (m + 1 >= col) ? w1 : 0.f;
                w2 = (m + 2 >= col) ? w2 : 0.f;
                w3 = (m + 3 >= col) ? w3 : 0.f;
                s0 = fmaf(l0, w0, s0);
                s1 = fmaf(l1, w1, s1);
                s2 = fmaf(l2, w2, s2);
                s3 = fmaf(l3, w3, s3);
            }
            for (; m < i; ++m) {
                float l = Ls[i * ST1 + m];
                float w = Ls[col * ST1 + m];
                w = (m >= col) ? w : 0.f;
                s0 = fmaf(l, w, s0);
            }
            if (i >= col) {
                float del = (i == col) ? 1.0f : 0.0f;
                Ls[col * ST1 + i] = (del - ((s0 + s1) + (s2 + s3))) * invd[i];
            }
        }
    }
    __syncthreads();

    // store W col-major with explicit zeros above diag
    float* wp = wsW + (size_t)bk * Nn * Nn;
    #pragma unroll
    for (int it = 0; it < 25; ++it) {
        int t = tid + 256 * it;               // 0..6399
        int k = t / 80, m = t - 80 * k;
        wp[t] = (m >= k) ? Ls[k * ST1 + m] : 0.0f;
    }
}

// ---------------- Kernel 2: balanced triangular GEMM  Z = W*(X - mu), quad ----------
#define TS  128
#define STX 132

__global__ __launch_bounds__(320) void ll_kernel(
    const float* __restrict__ x,
    const float* __restrict__ mu,
    const float* __restrict__ wsW,
    const float* __restrict__ wsL,
    float* __restrict__ out)
{
    __shared__ float WC[Nn * Nn];          // col-major W
    __shared__ float XT[(Nn + 1) * STX];   // +1 padding row: safe unconditional prefetch
    __shared__ float mus[Nn];

    const int bk  = blockIdx.x;
    const int st  = blockIdx.y;
    const int b   = bk / Kk;
    const int k   = bk - b * Kk;
    const int s0  = st * TS;
    const int tid = threadIdx.x;
    const int rg  = tid >> 5;        // 0..9
    const int cg  = tid & 31;        // 0..31

    if (tid < Nn) mus[tid] = mu[(size_t)bk * Nn + tid];
    {
        const float4* wp = (const float4*)(wsW + (size_t)bk * Nn * Nn);
        float4* wl = (float4*)WC;
        #pragma unroll
        for (int t = 0; t < 5; ++t) wl[tid + 320 * t] = wp[tid + 320 * t];
    }
    __syncthreads();

    // stage + transpose (x - mu)
    #pragma unroll
    for (int it = 0; it < 8; ++it) {
        int cI = tid + 320 * it;                 // 0..2559
        int sr = cI / 20, q = cI - 20 * sr;
        int s  = s0 + sr;
        float4 v = make_float4(0.f, 0.f, 0.f, 0.f);
        if (s < Ss) v = *(const float4*)(x + ((size_t)b * Ss + s) * Nn + 4 * q);
        float v0 = v.x - mus[4 * q + 0];
        float v1 = v.y - mus[4 * q + 1];
        float v2 = v.z - mus[4 * q + 2];
        float v3 = v.w - mus[4 * q + 3];
        #pragma unroll
        for (int n = 0; n < 4; ++n) {
            int i = (n + q) & 3;
            float val = (i == 0) ? v0 : (i == 1) ? v1 : (i == 2) ? v2 : v3;
            XT[(4 * q + i) * STX + sr] = val;
        }
    }
    __syncthreads();

    // balanced split tile: rows [4rg,4rg+4) + [76-4rg,80-4rg), 4 cols; prefetched k-loop
    const int a0 = 4 * rg;
    const int b0 = 76 - 4 * rg;
    const int e1 = a0 + 4;
    const int e2 = b0 + 4;
    float aA[4][4], aB[4][4];
    #pragma unroll
    for (int r = 0; r < 4; ++r)
        #pragma unroll
        for (int j = 0; j < 4; ++j) { aA[r][j] = 0.f; aB[r][j] = 0.f; }

    float4 xf = *(const float4*)&XT[4 * cg];
    float4 wa = *(const float4*)&WC[a0];
    float4 wb = *(const float4*)&WC[b0];

    #pragma unroll 4
    for (int kk = 0; kk < e1; ++kk) {
        const int nk = kk + 1;                    // nk <= e1 <= 40: always in-bounds
        float4 xf_n = *(const float4*)&XT[nk * STX + 4 * cg];
        float4 wa_n = *(const float4*)&WC[nk * Nn + a0];
        float4 wb_n = *(const float4*)&WC[nk * Nn + b0];
        float xv[4]  = {xf.x, xf.y, xf.z, xf.w};
        float wav[4] = {wa.x, wa.y, wa.z, wa.w};
        float wbv[4] = {wb.x, wb.y, wb.z, wb.w};
        #pragma unroll
        for (int r = 0; r < 4; ++r)
            #pragma unroll
            for (int j = 0; j < 4; ++j) {
                aA[r][j] = fmaf(wav[r], xv[j], aA[r][j]);
                aB[r][j] = fmaf(wbv[r], xv[j], aB[r][j]);
            }
        xf = xf_n; wa = wa_n; wb = wb_n;
    }
    #pragma unroll 4
    for (int kk = e1; kk < e2; ++kk) {
        const int nk = kk + 1;                    // nk <= 80: XT padded, WC spills into XT (harmless)
        float4 xf_n = *(const float4*)&XT[nk * STX + 4 * cg];
        float4 wb_n = *(const float4*)&WC[nk * Nn + b0];
        float xv[4]  = {xf.x, xf.y, xf.z, xf.w};
        float wbv[4] = {wb.x, wb.y, wb.z, wb.w};
        #pragma unroll
        for (int r = 0; r < 4; ++r)
            #pragma unroll
            for (int j = 0; j < 4; ++j)
                aB[r][j] = fmaf(wbv[r], xv[j], aB[r][j]);
        xf = xf_n; wb = wb_n;
    }
    __syncthreads();

    // per-(thread,col) partial quad -> b128 write -> reduce 10 row-groups
    float pj[4];
    #pragma unroll
    for (int j = 0; j < 4; ++j) {
        float t = 0.f;
        #pragma unroll
        for (int r = 0; r < 4; ++r) {
            t = fmaf(aA[r][j], aA[r][j], t);
            t = fmaf(aB[r][j], aB[r][j], t);
        }
        pj[j] = t;
    }
    *(float4*)&XT[rg * TS + 4 * cg] = make_float4(pj[0], pj[1], pj[2], pj[3]);
    __syncthreads();

    if (tid < TS) {
        float q2 = 0.f;
        #pragma unroll
        for (int g = 0; g < 10; ++g) q2 += XT[g * TS + tid];
        int s = s0 + tid;
        if (s < Ss)
            out[((size_t)b * Ss + s) * Kk + k] = -0.5f * q2 - wsL[bk] - CTERM;
    }
}

// ---------------- Fallback if workspace too small ----------------
__global__ __launch_bounds__(256) void mvn_ll_fallback(
    const float* __restrict__ x, const float* __restrict__ mu,
    const float* __restrict__ sigma, float* __restrict__ out)
{
    __shared__ float Ls[Nn * ST1];
    __shared__ float invd[Nn];
    __shared__ float mus[Nn];
    __shared__ float logdet_s;

    const int bk = blockIdx.x, b = bk / Kk, k = bk - b * Kk;
    const int tid = threadIdx.x, nt = blockDim.x;

    const float* sp = sigma + (size_t)bk * Nn * Nn;
    for (int t = tid; t < Nn * Nn; t += nt) Ls[(t / Nn) * ST1 + (t % Nn)] = sp[t];
    if (tid < Nn) mus[tid] = mu[(size_t)bk * Nn + tid];
    __syncthreads();
    if (tid < Nn) Ls[tid * ST1 + tid] += 1e-5f;
    __syncthreads();
    for (int j = 0; j < Nn; ++j) {
        if (tid == 0) {
            float d = sqrtf(Ls[j * ST1 + j]);
            Ls[j * ST1 + j] = d; invd[j] = 1.0f / d;
        }
        __syncthreads();
        const float inv = invd[j];
        for (int i = j + 1 + tid; i < Nn; i += nt) Ls[i * ST1 + j] *= inv;
        __syncthreads();
        for (int t = tid; t < Nn * Nn; t += nt) {
            int r = t / Nn, c = t % Nn;
            if (r > j && c > j && c <= r)
                Ls[r * ST1 + c] -= Ls[r * ST1 + j] * Ls[c * ST1 + j];
        }
        __syncthreads();
    }
    if (tid == 0) {
        float a = 0.f; for (int j = 0; j < Nn; ++j) a += logf(Ls[j * ST1 + j]);
        logdet_s = a;
    }
    __syncthreads();
    const float ld = logdet_s;
    for (int s = tid; s < Ss; s += nt) {
        const float4* xp = (const float4*)(x + ((size_t)b * Ss + s) * Nn);
        float a[Nn];
        #pragma unroll
        for (int q = 0; q < Nn / 4; ++q) {
            float4 v = xp[q];
            a[4*q+0] = v.x - mus[4*q+0]; a[4*q+1] = v.y - mus[4*q+1];
            a[4*q+2] = v.z - mus[4*q+2]; a[4*q+3] = v.w - mus[4*q+3];
        }
        #pragma unroll
        for (int i = 0; i < Nn; ++i) {
            float t = a[i];
            #pragma unroll
            for (int j = 0; j < i; ++j) t = fmaf(-Ls[i * ST1 + j], a[j], t);
            a[i] = t * invd[i];
        }
        float quad = 0.f;
        #pragma unroll
        for (int i = 0; i < Nn; ++i) quad = fmaf(a[i], a[i], quad);
        out[((size_t)b * Ss + s) * Kk + k] = -0.5f * quad - ld - CTERM;
    }
}

extern "C" void kernel_launch(void* const* d_in, const int* in_sizes, int n_in,
                              void* d_out, int out_size, void* d_ws, size_t ws_size,
                              hipStream_t stream) {
    const float* x     = (const float*)d_in[0];
    const float* mu    = (const float*)d_in[1];
    const float* sigma = (const float*)d_in[2];
    float* out = (float*)d_out;

    const size_t nBK  = (size_t)Bb * Kk;                    // 768
    const size_t need = nBK * Nn * Nn * 4 + nBK * 4;

    if (ws_size >= need) {
        float* wsW = (float*)d_ws;
        float* wsL = wsW + nBK * Nn * Nn;
        prep_kernel<<<dim3(Bb * Kk), dim3(256), 0, stream>>>(sigma, wsW, wsL);
        ll_kernel<<<dim3(Bb * Kk, (Ss + TS - 1) / TS), dim3(320), 0, stream>>>(x, mu, wsW, wsL, out);
    } else {
        mvn_ll_fallback<<<dim3(Bb * Kk), dim3(256), 0, stream>>>(x, mu, sigma, out);
    }
}

// Round 5
// 386.455 us; speedup vs baseline: 2.2081x; 1.2734x over previous
//
#include <hip/hip_runtime.h>

#define Bb 64
#define Ss 1000
#define Kk 12
#define Nn 80
#define CTERM 73.51508265637381f   // 0.5 * 80 * log(2*pi)

typedef __attribute__((ext_vector_type(8))) short short8;
typedef __attribute__((ext_vector_type(4))) float f32x4;

static __device__ __forceinline__ unsigned short f2bf(float f) {
    unsigned u = __builtin_bit_cast(unsigned, f);
    unsigned r = u + 0x7FFFu + ((u >> 16) & 1u);   // round-to-nearest-even
    return (unsigned short)(r >> 16);
}
static __device__ __forceinline__ float bf2f(unsigned short h) {
    unsigned u = ((unsigned)h) << 16;
    return __builtin_bit_cast(float, u);
}

// ================= Kernel 1: wave-per-matrix Cholesky -> W=L^{-1} (bf16 hi/lo) =========
#define STC 84   // fp32 LDS stride: 84*4=336 B, 336 mod 128 = 80, gcd(80,128)=16 -> full 32-bank spread

__global__ __launch_bounds__(64) void prep_kernel(
    const float* __restrict__ sigma,
    unsigned short* __restrict__ wsWhi,  // [768][80*80] row-major W[m][k], bf16 hi
    unsigned short* __restrict__ wsWlo,  // [768][80*80] bf16 lo
    float* __restrict__ wsL)             // [768] logdet_half
{
    __shared__ float Ls[Nn * STC];   // lower: L; upper(incl diag, packed): W[i][col] at Ls[col*STC+i]
    __shared__ float colbuf[Nn];
    __shared__ float invd[Nn];

    const int bk = blockIdx.x;
    const int l  = threadIdx.x;

    // stage sigma (row-major, stride-84)
    const float4* sp4 = (const float4*)(sigma + (size_t)bk * Nn * Nn);
    #pragma unroll
    for (int it = 0; it < 25; ++it) {
        int ci = l + 64 * it;            // 0..1599
        float4 v = sp4[ci];
        int r = ci / 20, c4 = 4 * (ci - 20 * (ci / 20));
        float* dst = &Ls[r * STC + c4];
        dst[0] = v.x; dst[1] = v.y; dst[2] = v.z; dst[3] = v.w;
    }
    __syncthreads();
    Ls[l * STC + l] += 1e-5f;
    if (l < 16) Ls[(l + 64) * STC + (l + 64)] += 1e-5f;
    __syncthreads();

    // ---- wave-synchronous Cholesky; lane owns rows l and l+64 ----
    float ldacc = 0.0f;
    const int r1 = l;
    const int r2 = l + 64;
    for (int j = 0; j < Nn; ++j) {
        float piv = Ls[j * STC + j];
        float inv = rsqrtf(piv);
        if (l == 0) { invd[j] = inv; ldacc += logf(piv); }
        const bool a1 = (r1 > j);
        const bool a2 = (l < 16) && (r2 > j);
        float c1 = 0.f, c2 = 0.f;
        if (a1) { c1 = Ls[r1 * STC + j] * inv; Ls[r1 * STC + j] = c1; colbuf[r1] = c1; }
        if (a2) { c2 = Ls[r2 * STC + j] * inv; Ls[r2 * STC + j] = c2; colbuf[r2] = c2; }
        __syncthreads();

        const int cs = j + 1;
        const int ca = (cs + 3) & ~3;
        for (int c = cs; c < ca && c < Nn; ++c) {      // scalar head (<=3 cols)
            float lc = colbuf[c];
            if (a1) Ls[r1 * STC + c] = fmaf(-c1, lc, Ls[r1 * STC + c]);
            if (a2) Ls[r2 * STC + c] = fmaf(-c2, lc, Ls[r2 * STC + c]);
        }
        for (int c = ca; c < Nn; c += 4) {             // vector body (rectangle: upper garbage OK)
            float4 lc = *(const float4*)&colbuf[c];    // broadcast
            if (a1) {
                float4 t = *(float4*)&Ls[r1 * STC + c];
                t.x = fmaf(-c1, lc.x, t.x); t.y = fmaf(-c1, lc.y, t.y);
                t.z = fmaf(-c1, lc.z, t.z); t.w = fmaf(-c1, lc.w, t.w);
                *(float4*)&Ls[r1 * STC + c] = t;
            }
            if (a2) {
                float4 t = *(float4*)&Ls[r2 * STC + c];
                t.x = fmaf(-c2, lc.x, t.x); t.y = fmaf(-c2, lc.y, t.y);
                t.z = fmaf(-c2, lc.z, t.z); t.w = fmaf(-c2, lc.w, t.w);
                *(float4*)&Ls[r2 * STC + c] = t;
            }
        }
        __syncthreads();
    }
    if (l == 0) wsL[bk] = 0.5f * ldacc;   // logdet_half = sum log(sqrt(piv))

    // ---- inversion pass 1: lane = column (0..63); W packed into upper: Ls[col*STC+i] ----
    {
        const int col = l;
        for (int i = 0; i < Nn; ++i) {
            float s0 = 0.f, s1 = 0.f, s2 = 0.f, s3 = 0.f;
            int m = 0;
            for (; m + 3 < i; m += 4) {
                float l0 = Ls[i * STC + m],     l1 = Ls[i * STC + m + 1];
                float l2 = Ls[i * STC + m + 2], l3 = Ls[i * STC + m + 3];
                float w0 = Ls[col * STC + m];     w0 = (m     >= col) ? w0 : 0.f;
                float w1 = Ls[col * STC + m + 1]; w1 = (m + 1 >= col) ? w1 : 0.f;
                float w2 = Ls[col * STC + m + 2]; w2 = (m + 2 >= col) ? w2 : 0.f;
                float w3 = Ls[col * STC + m + 3]; w3 = (m + 3 >= col) ? w3 : 0.f;
                s0 = fmaf(l0, w0, s0); s1 = fmaf(l1, w1, s1);
                s2 = fmaf(l2, w2, s2); s3 = fmaf(l3, w3, s3);
            }
            for (; m < i; ++m) {
                float lv = Ls[i * STC + m];
                float wv = Ls[col * STC + m]; wv = (m >= col) ? wv : 0.f;
                s0 = fmaf(lv, wv, s0);
            }
            if (i >= col)
                Ls[col * STC + i] = (((i == col) ? 1.f : 0.f) - ((s0 + s1) + (s2 + s3))) * invd[i];
        }
    }
    // ---- pass 2: lanes 0..15, columns 64..79 (only read rows/cols >= 64) ----
    if (l < 16) {
        const int col = l + 64;
        for (int i = 64; i < Nn; ++i) {
            float s = 0.f;
            for (int m = 64; m < i; ++m) {
                float lv = Ls[i * STC + m];
                float wv = Ls[col * STC + m]; wv = (m >= col) ? wv : 0.f;
                s = fmaf(lv, wv, s);
            }
            if (i >= col)
                Ls[col * STC + i] = (((i == col) ? 1.f : 0.f) - s) * invd[i];
        }
    }
    __syncthreads();

    // ---- write out hi/lo bf16, row-major W[m][k], pairs packed into uint ----
    unsigned* ph = (unsigned*)(wsWhi + (size_t)bk * Nn * Nn);
    unsigned* pl = (unsigned*)(wsWlo + (size_t)bk * Nn * Nn);
    #pragma unroll
    for (int it = 0; it < 50; ++it) {
        int ui = l + 64 * it;            // uint index 0..3199
        int t2 = 2 * ui;
        int m = t2 / 80, k = t2 - 80 * m;
        float wa = (k     <= m) ? Ls[k       * STC + m] : 0.f;
        float wb = (k + 1 <= m) ? Ls[(k + 1) * STC + m] : 0.f;
        unsigned short ha = f2bf(wa), hb = f2bf(wb);
        float la = wa - bf2f(ha), lb = wb - bf2f(hb);
        ph[ui] = (unsigned)ha | ((unsigned)hb << 16);
        pl[ui] = (unsigned)f2bf(la) | ((unsigned)f2bf(lb) << 16);
    }
}

// ================= Kernel 2: MFMA  Z = W*(X-mu), quad = colnorm^2 ======================
#define TS2 128   // s-tile
#define STW 104   // bf16 LDS stride (bytes 208: full bank spread, 16B aligned)

__global__ __launch_bounds__(512) void ll_kernel(
    const float* __restrict__ x,
    const float* __restrict__ mu,
    const unsigned short* __restrict__ wsWhi,
    const unsigned short* __restrict__ wsWlo,
    const float* __restrict__ wsL,
    float* __restrict__ out)
{
    __shared__ unsigned short Wh[Nn * STW];    // 16640 B
    __shared__ unsigned short Wl[Nn * STW];
    __shared__ unsigned short Dh[TS2 * STW];   // 26624 B
    __shared__ unsigned short Dl[TS2 * STW];
    __shared__ float mus[Nn];

    const int bk  = blockIdx.x;
    const int st  = blockIdx.y;
    const int b   = bk / Kk;
    const int k   = bk - b * Kk;
    const int s0  = st * TS2;
    const int tid = threadIdx.x;

    if (tid < Nn) mus[tid] = mu[(size_t)bk * Nn + tid];

    // stage W hi/lo: 80 rows x 80 k (8-bf16 chunks), pad k=80..95 with zeros
    #pragma unroll
    for (int it = 0; it < 2; ++it) {
        int c = tid + 512 * it;
        if (c < 800) {
            int r = c / 10, q = c - 10 * r;
            *(uint4*)&Wh[r * STW + 8 * q] = *(const uint4*)(wsWhi + (size_t)bk * 6400 + r * 80 + 8 * q);
            *(uint4*)&Wl[r * STW + 8 * q] = *(const uint4*)(wsWlo + (size_t)bk * 6400 + r * 80 + 8 * q);
        }
    }
    if (tid < 160) {
        int r = tid >> 1, q = 10 + (tid & 1);
        uint4 z = make_uint4(0, 0, 0, 0);
        *(uint4*)&Wh[r * STW + 8 * q] = z;
        *(uint4*)&Wl[r * STW + 8 * q] = z;
    }
    __syncthreads();

    // stage D = x - mu as bf16 hi/lo, layout Dh[s][k], k padded to 96 with zeros
    #pragma unroll
    for (int it = 0; it < 3; ++it) {
        int c = tid + 512 * it;                 // 0..1535 = 128 s x 12 chunks
        int s = c / 12, ch = c - 12 * s;
        int gs = s0 + s;
        uint4 vh = make_uint4(0, 0, 0, 0), vl = vh;
        if (ch < 10 && gs < Ss) {
            const float* xp = x + ((size_t)b * Ss + gs) * Nn + 8 * ch;
            float4 f0 = *(const float4*)xp;
            float4 f1 = *(const float4*)(xp + 4);
            float d[8] = {f0.x, f0.y, f0.z, f0.w, f1.x, f1.y, f1.z, f1.w};
            unsigned hh[8], ll2[8];
            #pragma unroll
            for (int i = 0; i < 8; ++i) {
                float dv = d[i] - mus[8 * ch + i];
                unsigned short h = f2bf(dv);
                float lo = dv - bf2f(h);
                hh[i] = h; ll2[i] = f2bf(lo);
            }
            vh = make_uint4(hh[0] | (hh[1] << 16), hh[2] | (hh[3] << 16),
                            hh[4] | (hh[5] << 16), hh[6] | (hh[7] << 16));
            vl = make_uint4(ll2[0] | (ll2[1] << 16), ll2[2] | (ll2[3] << 16),
                            ll2[4] | (ll2[5] << 16), ll2[6] | (ll2[7] << 16));
        }
        *(uint4*)&Dh[s * STW + 8 * ch] = vh;
        *(uint4*)&Dl[s * STW + 8 * ch] = vl;
    }
    __syncthreads();

    // ---- MFMA: wave w owns s-cols [16w,16w+16); A = W rows (5 m-tiles), K = 96 ----
    const int wv   = tid >> 6;
    const int lane = tid & 63;
    const int n    = lane & 15;
    const int quad = lane >> 4;

    f32x4 acc[5];
    #pragma unroll
    for (int mt = 0; mt < 5; ++mt) acc[mt] = (f32x4){0.f, 0.f, 0.f, 0.f};

    #pragma unroll
    for (int ks = 0; ks < 3; ++ks) {
        const int kof = 32 * ks + 8 * quad;
        short8 bh = *(const short8*)&Dh[(16 * wv + n) * STW + kof];
        short8 bl = *(const short8*)&Dl[(16 * wv + n) * STW + kof];
        #pragma unroll
        for (int mt = 0; mt < 5; ++mt) {
            short8 ah = *(const short8*)&Wh[(16 * mt + n) * STW + kof];
            short8 al = *(const short8*)&Wl[(16 * mt + n) * STW + kof];
            acc[mt] = __builtin_amdgcn_mfma_f32_16x16x32_bf16(ah, bh, acc[mt], 0, 0, 0);
            acc[mt] = __builtin_amdgcn_mfma_f32_16x16x32_bf16(al, bh, acc[mt], 0, 0, 0);
            acc[mt] = __builtin_amdgcn_mfma_f32_16x16x32_bf16(ah, bl, acc[mt], 0, 0, 0);
        }
    }

    // quad per s-col: sum 20 squares per lane, then reduce across the 4 row-quads
    float q2 = 0.f;
    #pragma unroll
    for (int mt = 0; mt < 5; ++mt)
        #pragma unroll
        for (int r = 0; r < 4; ++r)
            q2 = fmaf(acc[mt][r], acc[mt][r], q2);
    q2 += __shfl_xor(q2, 16, 64);
    q2 += __shfl_xor(q2, 32, 64);

    int gs = s0 + 16 * wv + n;
    if (lane < 16 && gs < Ss) {
        float ld = wsL[bk];
        out[((size_t)b * Ss + gs) * Kk + k] = -0.5f * q2 - ld - CTERM;
    }
}

// ================= Fallback (ws too small): round-1 style fused kernel =================
#define ST1 81
__global__ __launch_bounds__(256) void mvn_ll_fallback(
    const float* __restrict__ x, const float* __restrict__ mu,
    const float* __restrict__ sigma, float* __restrict__ out)
{
    __shared__ float Ls[Nn * ST1];
    __shared__ float invd[Nn];
    __shared__ float mus[Nn];
    __shared__ float logdet_s;

    const int bk = blockIdx.x, b = bk / Kk, k = bk - b * Kk;
    const int tid = threadIdx.x, nt = blockDim.x;

    const float* sp = sigma + (size_t)bk * Nn * Nn;
    for (int t = tid; t < Nn * Nn; t += nt) Ls[(t / Nn) * ST1 + (t % Nn)] = sp[t];
    if (tid < Nn) mus[tid] = mu[(size_t)bk * Nn + tid];
    __syncthreads();
    if (tid < Nn) Ls[tid * ST1 + tid] += 1e-5f;
    __syncthreads();
    for (int j = 0; j < Nn; ++j) {
        if (tid == 0) {
            float d = sqrtf(Ls[j * ST1 + j]);
            Ls[j * ST1 + j] = d; invd[j] = 1.0f / d;
        }
        __syncthreads();
        const float inv = invd[j];
        for (int i = j + 1 + tid; i < Nn; i += nt) Ls[i * ST1 + j] *= inv;
        __syncthreads();
        for (int t = tid; t < Nn * Nn; t += nt) {
            int r = t / Nn, c = t % Nn;
            if (r > j && c > j && c <= r)
                Ls[r * ST1 + c] -= Ls[r * ST1 + j] * Ls[c * ST1 + j];
        }
        __syncthreads();
    }
    if (tid == 0) {
        float a = 0.f; for (int j = 0; j < Nn; ++j) a += logf(Ls[j * ST1 + j]);
        logdet_s = a;
    }
    __syncthreads();
    const float ld = logdet_s;
    for (int s = tid; s < Ss; s += nt) {
        const float4* xp = (const float4*)(x + ((size_t)b * Ss + s) * Nn);
        float a[Nn];
        #pragma unroll
        for (int q = 0; q < Nn / 4; ++q) {
            float4 v = xp[q];
            a[4*q+0] = v.x - mus[4*q+0]; a[4*q+1] = v.y - mus[4*q+1];
            a[4*q+2] = v.z - mus[4*q+2]; a[4*q+3] = v.w - mus[4*q+3];
        }
        #pragma unroll
        for (int i = 0; i < Nn; ++i) {
            float t = a[i];
            #pragma unroll
            for (int j = 0; j < i; ++j) t = fmaf(-Ls[i * ST1 + j], a[j], t);
            a[i] = t * invd[i];
        }
        float quad = 0.f;
        #pragma unroll
        for (int i = 0; i < Nn; ++i) quad = fmaf(a[i], a[i], quad);
        out[((size_t)b * Ss + s) * Kk + k] = -0.5f * quad - ld - CTERM;
    }
}

extern "C" void kernel_launch(void* const* d_in, const int* in_sizes, int n_in,
                              void* d_out, int out_size, void* d_ws, size_t ws_size,
                              hipStream_t stream) {
    const float* x     = (const float*)d_in[0];
    const float* mu    = (const float*)d_in[1];
    const float* sigma = (const float*)d_in[2];
    float* out = (float*)d_out;

    const size_t nBK  = (size_t)Bb * Kk;                         // 768
    const size_t need = nBK * Nn * Nn * 2 * 2 + nBK * 4;         // Whi+Wlo bf16 + logdet

    if (ws_size >= need) {
        unsigned short* wsWhi = (unsigned short*)d_ws;
        unsigned short* wsWlo = wsWhi + nBK * Nn * Nn;
        float*          wsL   = (float*)(wsWlo + nBK * Nn * Nn);
        prep_kernel<<<dim3(Bb * Kk), dim3(64), 0, stream>>>(sigma, wsWhi, wsWlo, wsL);
        ll_kernel<<<dim3(Bb * Kk, (Ss + TS2 - 1) / TS2), dim3(512), 0, stream>>>(
            x, mu, wsWhi, wsWlo, wsL, out);
    } else {
        mvn_ll_fallback<<<dim3(Bb * Kk), dim3(256), 0, stream>>>(x, mu, sigma, out);
    }
}